// Round 1
// baseline (271.366 us; speedup 1.0000x reference)
//
#include <hip/hip_runtime.h>

// Sequential2D: out[i] = sum_{j in [max(0,i-2), i]} X[j] @ W[i,j]^T + sum_j b[i,j]
// X (8,32768,128) f32, W (8,8,128,128) f32, b (8,8,128) f32, out (8,32768,128) f32.
//
// R3: barrier-free steady state. Only W (the shared operand) is staged in LDS,
// once per j (<=3 stages per wg). X is loaded straight from global into MFMA
// A-fragment registers (per-lane float4 pairs, rows contiguous in memory) and
// converted f32->bf16 in-register; next k-step's X is prefetched (depth-1 reg
// double buffer). No __syncthreads between k-steps -> waves keep ~4KB of loads
// in flight each, saturating HBM instead of parking at barriers.

#define NOUT  8
#define NIN   8
#define DD    128
#define BATCH 32768
#define BAND  2

#define BM    128        // batch rows per workgroup (4 waves x 32 rows)
#define WROWS 32         // rows per wave (2 m-fragments of 16)
#define SKW   136        // padded LDS stride for W tile (shorts): 272B/row -> 2-way max (free)

typedef __attribute__((ext_vector_type(8))) short  short8;
typedef __attribute__((ext_vector_type(4))) float  floatx4;

__device__ __forceinline__ unsigned short f2bf(float f) {
    unsigned int u = __float_as_uint(f);
    u += 0x7fffu + ((u >> 16) & 1u);
    return (unsigned short)(u >> 16);
}

__device__ __forceinline__ short8 pack8(floatx4 f0, floatx4 f1) {
    short8 p;
    p[0] = (short)f2bf(f0[0]); p[1] = (short)f2bf(f0[1]);
    p[2] = (short)f2bf(f0[2]); p[3] = (short)f2bf(f0[3]);
    p[4] = (short)f2bf(f1[0]); p[5] = (short)f2bf(f1[1]);
    p[6] = (short)f2bf(f1[2]); p[7] = (short)f2bf(f1[3]);
    return p;
}

__global__ __launch_bounds__(256, 3)
void seq2d_kernel(const float* __restrict__ X,
                  const float* __restrict__ W,
                  const float* __restrict__ Bv,
                  float* __restrict__ out) {
    const int i  = blockIdx.y;
    const int m0 = blockIdx.x * BM;

    __shared__ unsigned short sW[DD * SKW];   // one W block, bf16, n-major, padded
    __shared__ float sbias[DD];

    const int tid  = threadIdx.x;
    const int lane = tid & 63;
    const int wave = tid >> 6;          // 0..3
    const int l15  = lane & 15;
    const int quad = lane >> 4;
    const int wrow = wave * WROWS;      // this wave's first batch row in the tile

    int jlo = i - BAND; if (jlo < 0) jlo = 0;
    const int ncs = (i - jlo + 1) * 4;  // total k-steps of 32 across the band

    // Per-lane A-fragment base: row = m0 + wrow + (lane&15), k-offset = quad*8.
    // Fragment 1 is +16 rows. Each fragment load = 2 contiguous float4 (32B/lane).
    const float* xb = X + (size_t)(m0 + wrow + l15) * DD + quad * 8;

    floatx4 px[2][2][2];  // [parity][mfrag][half] — all indices compile-time after unroll

    auto prefetch = [&](int par, int c) {
        const int j  = jlo + (c >> 2);
        const int k0 = (c & 3) * 32;
        const float* p = xb + (size_t)j * (BATCH * DD) + k0;
        px[par][0][0] = *(const floatx4*)(p);
        px[par][0][1] = *(const floatx4*)(p + 4);
        px[par][1][0] = *(const floatx4*)(p + 16 * DD);
        px[par][1][1] = *(const floatx4*)(p + 16 * DD + 4);
    };

    prefetch(0, 0);   // first k-step's X in flight before anything else

    if (tid < DD) {
        float s = 0.f;
        for (int j = jlo; j <= i; ++j)
            s += Bv[(i * NIN + j) * DD + tid];
        sbias[tid] = s;
    }

    floatx4 acc[2][8];
#pragma unroll
    for (int a = 0; a < 2; ++a)
#pragma unroll
        for (int n = 0; n < 8; ++n)
            acc[a][n] = (floatx4){0.f, 0.f, 0.f, 0.f};

    // W staging geometry: 4 passes of 32 rows; thread t covers row (p*32 + t>>3),
    // cols (t&7)*16 .. +15  -> 4 float4 loads, 2 short8 LDS writes per pass.
    const int wr_r = tid >> 3;          // 0..31
    const int wr_c = (tid & 7) << 4;    // 0..112 step 16

    int c = 0;
    for (int j = jlo; j <= i; ++j) {
        const float* wsrc = W + (size_t)(i * NIN + j) * DD * DD;
        __syncthreads();                 // previous j's B-frag reads done
#pragma unroll
        for (int p = 0; p < 4; ++p) {
            const int r = p * 32 + wr_r;
            const float* wp = wsrc + (size_t)r * DD + wr_c;
            floatx4 w0 = *(const floatx4*)(wp);
            floatx4 w1 = *(const floatx4*)(wp + 4);
            floatx4 w2 = *(const floatx4*)(wp + 8);
            floatx4 w3 = *(const floatx4*)(wp + 12);
            *(short8*)&sW[r * SKW + wr_c]     = pack8(w0, w1);
            *(short8*)&sW[r * SKW + wr_c + 8] = pack8(w2, w3);
        }
        __syncthreads();                 // W tile visible to all waves

        // Barrier-free MFMA phase: 4 k-steps of 32, depth-1 X prefetch.
#pragma unroll
        for (int ks = 0; ks < 4; ++ks) {
            const int par = ks & 1;      // parity consistent across j (4 steps/j)
            if (c + 1 < ncs) prefetch(par ^ 1, c + 1);

            short8 a0 = pack8(px[par][0][0], px[par][0][1]);
            short8 a1 = pack8(px[par][1][0], px[par][1][1]);

            short8 bf[8];
#pragma unroll
            for (int nf = 0; nf < 8; ++nf)
                bf[nf] = *(const short8*)&sW[(nf * 16 + l15) * SKW + ks * 32 + quad * 8];

#pragma unroll
            for (int nf = 0; nf < 8; ++nf) {
                acc[0][nf] = __builtin_amdgcn_mfma_f32_16x16x32_bf16(a0, bf[nf], acc[0][nf], 0, 0, 0);
                acc[1][nf] = __builtin_amdgcn_mfma_f32_16x16x32_bf16(a1, bf[nf], acc[1][nf], 0, 0, 0);
            }
            ++c;
        }
    }

    // epilogue: C/D layout row=(lane>>4)*4+r, col=lane&15 (verified R1)
    float* outi = out + (size_t)i * BATCH * DD;
#pragma unroll
    for (int mf = 0; mf < 2; ++mf) {
#pragma unroll
        for (int nf = 0; nf < 8; ++nf) {
            const int n_g  = nf * 16 + l15;
            const float bs = sbias[n_g];
            const int m_b  = m0 + wrow + mf * 16 + quad * 4;
#pragma unroll
            for (int r = 0; r < 4; ++r)
                outi[(size_t)(m_b + r) * DD + n_g] = acc[mf][nf][r] + bs;
        }
    }
}

extern "C" void kernel_launch(void* const* d_in, const int* in_sizes, int n_in,
                              void* d_out, int out_size, void* d_ws, size_t ws_size,
                              hipStream_t stream) {
    const float* X  = (const float*)d_in[0];
    const float* W  = (const float*)d_in[1];
    const float* Bv = (const float*)d_in[2];
    float* out = (float*)d_out;

    dim3 grid(BATCH / BM, NOUT);
    seq2d_kernel<<<grid, 256, 0, stream>>>(X, W, Bv, out);
}